// Round 2
// baseline (1077.352 us; speedup 1.0000x reference)
//
#include <hip/hip_runtime.h>
#include <hip/hip_bf16.h>
#include <math.h>

// Problem constants
#define TOKENS   8192
#define DIM      4096
#define NEXP     256
#define TOPK     8
#define CAND     12      // fp32 candidates refined in fp64

// GEMM tiling
#define M_TILE   32
#define KC       32
#define GEMM_THREADS 512

// ---------------------------------------------------------------------------
// Kernel 1: logits = x @ W^T   (fp32 vector GEMM)  — approximate stage A.
// Only needs ~1e-2 absolute accuracy (candidate containment); fp32 gives 1e-5.
// ---------------------------------------------------------------------------
__global__ __launch_bounds__(GEMM_THREADS)
void gemm_logits(const float* __restrict__ x,
                 const float* __restrict__ w,
                 float* __restrict__ logits) {
    __shared__ float xs[KC][M_TILE + 4];
    __shared__ float ws[KC][NEXP];

    const int t  = threadIdx.x;
    const int m0 = blockIdx.x * M_TILE;

    const int c0 = (t & 63) * 4;
    const int r0 = (t >> 6) * 4;

    const int xlr = t >> 4;
    const int xlk = (t & 15) * 2;

    const int we  = t >> 1;
    const int wkh = (t & 1) * 16;

    float acc0[4][4], acc1[4][4];
    #pragma unroll
    for (int i = 0; i < 4; ++i)
        #pragma unroll
        for (int j = 0; j < 4; ++j) { acc0[i][j] = 0.f; acc1[i][j] = 0.f; }

    for (int k0 = 0; k0 < DIM; k0 += KC) {
        const float2 xv = *(const float2*)(x + (size_t)(m0 + xlr) * DIM + k0 + xlk);
        xs[xlk    ][xlr] = xv.x;
        xs[xlk + 1][xlr] = xv.y;

        #pragma unroll
        for (int j = 0; j < 4; ++j) {
            const float4 wv = *(const float4*)(w + (size_t)we * DIM + k0 + wkh + j * 4);
            ws[wkh + j*4 + 0][we] = wv.x;
            ws[wkh + j*4 + 1][we] = wv.y;
            ws[wkh + j*4 + 2][we] = wv.z;
            ws[wkh + j*4 + 3][we] = wv.w;
        }
        __syncthreads();

        #pragma unroll
        for (int k = 0; k < KC; k += 2) {
            {
                const float4 wv  = *(const float4*)&ws[k][c0];
                const float4 xv4 = *(const float4*)&xs[k][r0];
                const float xr[4] = {xv4.x, xv4.y, xv4.z, xv4.w};
                const float wr[4] = {wv.x, wv.y, wv.z, wv.w};
                #pragma unroll
                for (int i = 0; i < 4; ++i)
                    #pragma unroll
                    for (int j = 0; j < 4; ++j)
                        acc0[i][j] = fmaf(xr[i], wr[j], acc0[i][j]);
            }
            {
                const float4 wv  = *(const float4*)&ws[k + 1][c0];
                const float4 xv4 = *(const float4*)&xs[k + 1][r0];
                const float xr[4] = {xv4.x, xv4.y, xv4.z, xv4.w};
                const float wr[4] = {wv.x, wv.y, wv.z, wv.w};
                #pragma unroll
                for (int i = 0; i < 4; ++i)
                    #pragma unroll
                    for (int j = 0; j < 4; ++j)
                        acc1[i][j] = fmaf(xr[i], wr[j], acc1[i][j]);
            }
        }
        __syncthreads();
    }

    #pragma unroll
    for (int i = 0; i < 4; ++i) {
        float4 o;
        o.x = acc0[i][0] + acc1[i][0];
        o.y = acc0[i][1] + acc1[i][1];
        o.z = acc0[i][2] + acc1[i][2];
        o.w = acc0[i][3] + acc1[i][3];
        *(float4*)(logits + (size_t)(m0 + r0 + i) * NEXP + c0) = o;
    }
}

// ---------------------------------------------------------------------------
// Kernel 2: per-token top-CAND candidate selection from fp32 logits.
// One wave per token; lane holds 4 logits (expert = j*64 + lane).
// Monotonic sigmoid => select on raw logits. Ties: lower index.
// ---------------------------------------------------------------------------
__global__ __launch_bounds__(256)
void topk_cand(const float* __restrict__ logits, int* __restrict__ cand) {
    const int lane  = threadIdx.x & 63;
    const int token = blockIdx.x * 4 + (threadIdx.x >> 6);
    const float* lp = logits + (size_t)token * NEXP;

    float s[4];
    #pragma unroll
    for (int j = 0; j < 4; ++j) s[j] = lp[j * 64 + lane];

    int mye = 0;

    #pragma unroll
    for (int r = 0; r < CAND; ++r) {
        float bv = s[0];
        int   be = lane;
        #pragma unroll
        for (int j = 1; j < 4; ++j) {
            if (s[j] > bv) { bv = s[j]; be = j * 64 + lane; }
        }
        #pragma unroll
        for (int off = 32; off > 0; off >>= 1) {
            const float ov = __shfl_xor(bv, off, 64);
            const int   oe = __shfl_xor(be, off, 64);
            if (ov > bv || (ov == bv && oe < be)) { bv = ov; be = oe; }
        }
        if (lane == r) mye = be;
        if ((be & 63) == lane) s[be >> 6] = -1e30f;
    }

    if (lane < CAND) cand[token * CAND + lane] = mye;
}

// ---------------------------------------------------------------------------
// Kernel 3: fp64 rescore of the CAND candidates; exact top-8 + normalize.
// One block (256 thr) per token. x row staged in LDS; W rows from L2.
// ---------------------------------------------------------------------------
__global__ __launch_bounds__(256)
void rescore_fp64(const float* __restrict__ x,
                  const float* __restrict__ w,
                  const int* __restrict__ cand,
                  float* __restrict__ out) {
    __shared__ float  xs[DIM];       // 16 KB
    __shared__ double cs[CAND];
    __shared__ int    ce[CAND];

    const int t     = threadIdx.x;
    const int token = blockIdx.x;

    // stage x row (coalesced float4)
    const float4* xp = (const float4*)(x + (size_t)token * DIM);
    #pragma unroll
    for (int i = 0; i < DIM / 4 / 256; ++i) {          // 4 iters
        const int idx = t + i * 256;
        *(float4*)&xs[idx * 4] = xp[idx];
    }
    if (t < CAND) ce[t] = cand[token * CAND + t];
    __syncthreads();

    const int wave = t >> 6, lane = t & 63;
    for (int c = wave; c < CAND; c += 4) {
        const int e = ce[c];
        const float* wp = w + (size_t)e * DIM;
        double acc = 0.0;
        for (int d = lane; d < DIM; d += 64)
            acc = fma((double)xs[d], (double)wp[d], acc);
        #pragma unroll
        for (int off = 32; off > 0; off >>= 1)
            acc += __shfl_xor(acc, off, 64);
        if (lane == 0) cs[c] = 1.0 / (1.0 + exp(-acc));
    }
    __syncthreads();

    if (t == 0) {
        double v[CAND]; int idx[CAND];
        #pragma unroll
        for (int i = 0; i < CAND; ++i) { v[i] = cs[i]; idx[i] = ce[i]; }
        double topv[TOPK]; int topi[TOPK]; double sum = 0.0;
        #pragma unroll
        for (int r = 0; r < TOPK; ++r) {
            int b = -1;
            for (int i = 0; i < CAND; ++i) {
                if (idx[i] < 0) continue;
                if (b < 0 || v[i] > v[b] || (v[i] == v[b] && idx[i] < idx[b])) b = i;
            }
            topv[r] = v[b]; topi[r] = idx[b]; sum += v[b]; idx[b] = -1;
        }
        #pragma unroll
        for (int r = 0; r < TOPK; ++r) {
            out[(size_t)token * TOPK + r] = (float)(topv[r] / sum);
            out[(size_t)TOKENS * TOPK + (size_t)token * TOPK + r] = (float)topi[r];
        }
    }
}

extern "C" void kernel_launch(void* const* d_in, const int* in_sizes, int n_in,
                              void* d_out, int out_size, void* d_ws, size_t ws_size,
                              hipStream_t stream) {
    const float* x = (const float*)d_in[0];   // [8192, 4096]
    const float* w = (const float*)d_in[1];   // [256, 4096]
    float* out     = (float*)d_out;           // 65536 gates + 65536 idx-as-float
    float* logits  = (float*)d_ws;            // 8 MB
    int*   cand    = (int*)((char*)d_ws + (size_t)TOKENS * NEXP * sizeof(float));

    gemm_logits<<<TOKENS / M_TILE, GEMM_THREADS, 0, stream>>>(x, w, logits);
    topk_cand<<<TOKENS / 4, 256, 0, stream>>>(logits, cand);
    rescore_fp64<<<TOKENS, 256, 0, stream>>>(x, w, cand, out);
}

// Round 3
// 548.607 us; speedup vs baseline: 1.9638x; 1.9638x over previous
//
#include <hip/hip_runtime.h>
#include <hip/hip_bf16.h>
#include <hip/hip_fp16.h>
#include <math.h>

// Problem constants
#define TOKENS   8192
#define DIM      4096
#define NEXP     256
#define TOPK     8
#define CAND     12      // fp16-GEMM candidates refined in fp64

// GEMM tiling
#define MT   16          // token rows per block
#define BK   64          // k-chunk
#define LDH  72          // padded LDS row stride (halves); 72*2=144 B keeps b128 alignment

typedef _Float16 f16x8 __attribute__((ext_vector_type(8)));
typedef _Float16 f16x4 __attribute__((ext_vector_type(4)));
typedef float    f32x4 __attribute__((ext_vector_type(4)));

// ---------------------------------------------------------------------------
// Kernel 0: W fp32 -> fp16 (1M elems, one-shot)
// ---------------------------------------------------------------------------
__global__ __launch_bounds__(256)
void convert_w(const float* __restrict__ w, _Float16* __restrict__ wh) {
    const int t = blockIdx.x * 256 + threadIdx.x;   // 65536 threads
    const float4* wp = (const float4*)w;
    f16x8* op = (f16x8*)wh;
    #pragma unroll
    for (int i = 0; i < 2; ++i) {
        const int o = i * 65536 + t;                // half8 chunk index
        const float4 a = wp[2 * o];
        const float4 b = wp[2 * o + 1];
        f16x8 h;
        h[0] = (_Float16)a.x; h[1] = (_Float16)a.y;
        h[2] = (_Float16)a.z; h[3] = (_Float16)a.w;
        h[4] = (_Float16)b.x; h[5] = (_Float16)b.y;
        h[6] = (_Float16)b.z; h[7] = (_Float16)b.w;
        op[o] = h;
    }
}

// ---------------------------------------------------------------------------
// Kernel 1: logits = x @ W^T via fp16 MFMA (approximate stage A, ~1e-3 abs).
// Block: 256 thr (4 waves), covers MT=16 tokens x all 256 experts -> x read once.
// Wave w owns experts [w*64, w*64+64). 16x16x32 MFMA, both frags K-contiguous.
// ---------------------------------------------------------------------------
__global__ __launch_bounds__(256)
void gemm_fp16(const float* __restrict__ x, const _Float16* __restrict__ wh,
               float* __restrict__ logits) {
    __shared__ _Float16 ah[MT][LDH];      // 2.3 KB
    __shared__ _Float16 bh[NEXP][LDH];    // 36.9 KB

    const int t    = threadIdx.x;
    const int wave = t >> 6, lane = t & 63;
    const int m0   = blockIdx.x * MT;
    const int n0   = wave * 64;

    // A stage: row = t>>4 (0..15), 4 consecutive k per thread
    const int ar = t >> 4, ak = (t & 15) * 4;
    // B stage: per chunk c: row = c*32 + (t>>3), 8 consecutive k per thread
    const int br = t >> 3, bk = (t & 7) * 8;

    // fragment addressing (A and B identical pattern: row-major [row][k])
    const int fm = lane & 15;            // fragment row
    const int fk = (lane >> 4) * 8;      // fragment k offset

    f32x4 acc[4];
    #pragma unroll
    for (int nt = 0; nt < 4; ++nt) acc[nt] = (f32x4){0.f, 0.f, 0.f, 0.f};

    for (int k0 = 0; k0 < DIM; k0 += BK) {
        // stage A (fp32 -> fp16 on the fly)
        const float4 xv = *(const float4*)(x + (size_t)(m0 + ar) * DIM + k0 + ak);
        f16x4 hx;
        hx[0] = (_Float16)xv.x; hx[1] = (_Float16)xv.y;
        hx[2] = (_Float16)xv.z; hx[3] = (_Float16)xv.w;
        *(f16x4*)&ah[ar][ak] = hx;

        // stage B (already fp16, 16B chunks, coalesced: 8 lanes span one row)
        #pragma unroll
        for (int c = 0; c < 8; ++c) {
            const f16x8 wv = *(const f16x8*)(wh + (size_t)(c * 32 + br) * DIM + k0 + bk);
            *(f16x8*)&bh[c * 32 + br][bk] = wv;
        }
        __syncthreads();

        #pragma unroll
        for (int kk = 0; kk < 2; ++kk) {
            const f16x8 af = *(const f16x8*)&ah[fm][kk * 32 + fk];
            #pragma unroll
            for (int nt = 0; nt < 4; ++nt) {
                const f16x8 bf = *(const f16x8*)&bh[n0 + nt * 16 + fm][kk * 32 + fk];
                acc[nt] = __builtin_amdgcn_mfma_f32_16x16x32_f16(af, bf, acc[nt], 0, 0, 0);
            }
        }
        __syncthreads();
    }

    // epilogue: C/D layout col=lane&15, row=(lane>>4)*4+reg  [m89/m91]
    #pragma unroll
    for (int nt = 0; nt < 4; ++nt) {
        #pragma unroll
        for (int r = 0; r < 4; ++r) {
            const int m = m0 + (lane >> 4) * 4 + r;
            const int n = n0 + nt * 16 + (lane & 15);
            logits[(size_t)m * NEXP + n] = acc[nt][r];
        }
    }
}

// ---------------------------------------------------------------------------
// Kernel 2: per-token top-CAND candidates from approx logits (monotonic sigmoid
// => select on raw logits). One wave per token. Ties: lower index.
// ---------------------------------------------------------------------------
__global__ __launch_bounds__(256)
void topk_cand(const float* __restrict__ logits, int* __restrict__ cand) {
    const int lane  = threadIdx.x & 63;
    const int token = blockIdx.x * 4 + (threadIdx.x >> 6);
    const float* lp = logits + (size_t)token * NEXP;

    float s[4];
    #pragma unroll
    for (int j = 0; j < 4; ++j) s[j] = lp[j * 64 + lane];

    int mye = 0;
    #pragma unroll
    for (int r = 0; r < CAND; ++r) {
        float bv = s[0];
        int   be = lane;
        #pragma unroll
        for (int j = 1; j < 4; ++j) {
            if (s[j] > bv) { bv = s[j]; be = j * 64 + lane; }
        }
        #pragma unroll
        for (int off = 32; off > 0; off >>= 1) {
            const float ov = __shfl_xor(bv, off, 64);
            const int   oe = __shfl_xor(be, off, 64);
            if (ov > bv || (ov == bv && oe < be)) { bv = ov; be = oe; }
        }
        if (lane == r) mye = be;
        if ((be & 63) == lane) s[be >> 6] = -1e30f;
    }

    if (lane < CAND) cand[token * CAND + lane] = mye;
}

// ---------------------------------------------------------------------------
// Kernel 3: fp64 rescore of CAND candidates, exact ordering, gates.
// Block (256 thr) per token; wave w handles candidates w, w+4, w+8.
// Vectorized: float4 global W loads + b128 LDS x reads, unrolled x16 so the
// compiler keeps 16 loads in flight (fixes round-1 latency serialization).
// ---------------------------------------------------------------------------
__global__ __launch_bounds__(256)
void rescore(const float* __restrict__ x, const float* __restrict__ w,
             const int* __restrict__ cand, float* __restrict__ out) {
    __shared__ float  xs[DIM];       // 16 KB
    __shared__ double sc[CAND];
    __shared__ int    ce[CAND];

    const int t = threadIdx.x, wave = t >> 6, lane = t & 63;
    const int token = blockIdx.x;

    const float4* xp4 = (const float4*)(x + (size_t)token * DIM);
    #pragma unroll
    for (int i = 0; i < 4; ++i)
        *(float4*)&xs[(t + i * 256) * 4] = xp4[t + i * 256];
    if (t < CAND) ce[t] = cand[token * CAND + t];
    __syncthreads();

    for (int c = wave; c < CAND; c += 4) {
        const float4* wp4 = (const float4*)(w + (size_t)ce[c] * DIM);
        double a0 = 0.0, a1 = 0.0, a2 = 0.0, a3 = 0.0;
        #pragma unroll
        for (int i = 0; i < 16; ++i) {
            const float4 wv = wp4[lane + i * 64];
            const float4 xv = *(const float4*)&xs[(lane + i * 64) * 4];
            a0 = fma((double)xv.x, (double)wv.x, a0);
            a1 = fma((double)xv.y, (double)wv.y, a1);
            a2 = fma((double)xv.z, (double)wv.z, a2);
            a3 = fma((double)xv.w, (double)wv.w, a3);
        }
        double acc = (a0 + a1) + (a2 + a3);
        #pragma unroll
        for (int off = 32; off > 0; off >>= 1)
            acc += __shfl_xor(acc, off, 64);
        if (lane == 0) sc[c] = acc;     // fp64 logit
    }
    __syncthreads();

    if (wave == 0) {
        double v  = (lane < CAND) ? sc[lane] : -1e300;
        int    ei = (lane < CAND) ? ce[lane] : 0x7fffffff;
        double myv = 0.0; int mye = 0;
        #pragma unroll
        for (int r = 0; r < TOPK; ++r) {
            double bv = v; int be = ei;
            #pragma unroll
            for (int off = 32; off > 0; off >>= 1) {
                const double ov = __shfl_xor(bv, off, 64);
                const int    oe = __shfl_xor(be, off, 64);
                if (ov > bv || (ov == bv && oe < be)) { bv = ov; be = oe; }
            }
            if (lane == r) { myv = bv; mye = be; }
            if (be == ei) v = -1e300;              // knock out winner
        }
        // fp64 sigmoid for the 8 winners (lane-parallel), fp64 normalize
        const double sig = (lane < TOPK) ? 1.0 / (1.0 + exp(-myv)) : 0.0;
        double sum = sig;
        #pragma unroll
        for (int off = 32; off > 0; off >>= 1)
            sum += __shfl_xor(sum, off, 64);
        if (lane < TOPK) {
            out[(size_t)token * TOPK + lane] = (float)(sig / sum);
            out[(size_t)TOKENS * TOPK + (size_t)token * TOPK + lane] = (float)mye;
        }
    }
}

extern "C" void kernel_launch(void* const* d_in, const int* in_sizes, int n_in,
                              void* d_out, int out_size, void* d_ws, size_t ws_size,
                              hipStream_t stream) {
    const float* x = (const float*)d_in[0];   // [8192, 4096]
    const float* w = (const float*)d_in[1];   // [256, 4096]
    float* out     = (float*)d_out;           // 65536 gates + 65536 idx-as-float

    // ws layout: logits fp32 (8 MB) | cand (384 KB) | wh fp16 (2 MB)
    float*     logits = (float*)d_ws;
    int*       candp  = (int*)((char*)d_ws + (size_t)TOKENS * NEXP * sizeof(float));
    _Float16*  wh     = (_Float16*)((char*)d_ws + (size_t)TOKENS * NEXP * sizeof(float)
                                                + (size_t)TOKENS * CAND * sizeof(int));

    convert_w<<<256, 256, 0, stream>>>(w, wh);
    gemm_fp16<<<TOKENS / MT, 256, 0, stream>>>(x, wh, logits);
    topk_cand<<<TOKENS / 4, 256, 0, stream>>>(logits, candp);
    rescore<<<TOKENS, 256, 0, stream>>>(x, w, candp, out);
}

// Round 4
// 523.440 us; speedup vs baseline: 2.0582x; 1.0481x over previous
//
#include <hip/hip_runtime.h>
#include <hip/hip_bf16.h>
#include <hip/hip_fp16.h>
#include <math.h>

// Problem constants
#define TOKENS   8192
#define DIM      4096
#define NEXP     256
#define TOPK     8
#define CAND     12      // fp16-GEMM candidates refined in fp64

// GEMM tiling
#define MT   32          // token rows per block
#define BK   64          // k-chunk
#define LDH  72          // padded LDS row stride in halves (144 B, 16B-aligned)

typedef _Float16 f16x8 __attribute__((ext_vector_type(8)));
typedef _Float16 f16x4 __attribute__((ext_vector_type(4)));
typedef float    f32x4 __attribute__((ext_vector_type(4)));

// ---------------------------------------------------------------------------
// Kernel 0: W fp32 -> fp16 (1M elems, one-shot)
// ---------------------------------------------------------------------------
__global__ __launch_bounds__(256)
void convert_w(const float* __restrict__ w, _Float16* __restrict__ wh) {
    const int t = blockIdx.x * 256 + threadIdx.x;
    const float4* wp = (const float4*)w;
    f16x8* op = (f16x8*)wh;
    #pragma unroll
    for (int i = 0; i < 2; ++i) {
        const int o = i * 65536 + t;
        const float4 a = wp[2 * o];
        const float4 b = wp[2 * o + 1];
        f16x8 h;
        h[0] = (_Float16)a.x; h[1] = (_Float16)a.y;
        h[2] = (_Float16)a.z; h[3] = (_Float16)a.w;
        h[4] = (_Float16)b.x; h[5] = (_Float16)b.y;
        h[6] = (_Float16)b.z; h[7] = (_Float16)b.w;
        op[o] = h;
    }
}

// ---------------------------------------------------------------------------
// Kernel 1: logits = x @ W^T via fp16 MFMA. MT=32 x all 256 experts per block,
// 512 thr = 8 waves, wave-tile 16x128 -> 8 MFMA / wave / BK. Register-prefetch
// pipeline: next k-chunk's global loads issue while MFMA consumes LDS.
// ---------------------------------------------------------------------------
__global__ __launch_bounds__(512)
void gemm_fp16(const float* __restrict__ x, const _Float16* __restrict__ wh,
               float* __restrict__ logits) {
    __shared__ _Float16 ah[MT][LDH];      // 4.6 KB
    __shared__ _Float16 bh[NEXP][LDH];    // 36.9 KB

    const int t    = threadIdx.x;
    const int wave = t >> 6, lane = t & 63;
    const int m0   = blockIdx.x * MT;
    const int wr   = (wave >> 2) * 16;    // wave row offset (0|16)
    const int wc   = (wave & 3) * 64;     // wave col offset (0..192)

    // A stage: row = t>>4 (0..31), 4 consecutive k (float4)
    const int ar = t >> 4, ak = (t & 15) * 4;
    // B stage: per chunk c: row = c*64 + (t>>3), 8 consecutive k (f16x8)
    const int br = t >> 3, bk = (t & 7) * 8;

    // fragment addressing
    const int fm = lane & 15;
    const int fk = (lane >> 4) * 8;

    f32x4 acc[4];
    #pragma unroll
    for (int nt = 0; nt < 4; ++nt) acc[nt] = (f32x4){0.f, 0.f, 0.f, 0.f};

    // prefetch k0 = 0
    float4 xa = *(const float4*)(x + (size_t)(m0 + ar) * DIM + ak);
    f16x8 wb[4];
    #pragma unroll
    for (int c = 0; c < 4; ++c)
        wb[c] = *(const f16x8*)(wh + (size_t)(c * 64 + br) * DIM + bk);

    for (int k0 = 0; k0 < DIM; k0 += BK) {
        // store staged regs to LDS
        f16x4 hx;
        hx[0] = (_Float16)xa.x; hx[1] = (_Float16)xa.y;
        hx[2] = (_Float16)xa.z; hx[3] = (_Float16)xa.w;
        *(f16x4*)&ah[ar][ak] = hx;
        #pragma unroll
        for (int c = 0; c < 4; ++c)
            *(f16x8*)&bh[c * 64 + br][bk] = wb[c];
        __syncthreads();

        // issue next chunk's loads (overlap with MFMA below)
        if (k0 + BK < DIM) {
            xa = *(const float4*)(x + (size_t)(m0 + ar) * DIM + k0 + BK + ak);
            #pragma unroll
            for (int c = 0; c < 4; ++c)
                wb[c] = *(const f16x8*)(wh + (size_t)(c * 64 + br) * DIM + k0 + BK + bk);
        }

        #pragma unroll
        for (int kk = 0; kk < 2; ++kk) {
            const f16x8 af = *(const f16x8*)&ah[wr + fm][kk * 32 + fk];
            #pragma unroll
            for (int nt = 0; nt < 4; ++nt) {
                const f16x8 bf = *(const f16x8*)&bh[wc + nt * 16 + fm][kk * 32 + fk];
                acc[nt] = __builtin_amdgcn_mfma_f32_16x16x32_f16(af, bf, acc[nt], 0, 0, 0);
            }
        }
        __syncthreads();
    }

    // epilogue: C/D layout col=lane&15, row=(lane>>4)*4+reg  [m89/m91]
    #pragma unroll
    for (int nt = 0; nt < 4; ++nt) {
        #pragma unroll
        for (int r = 0; r < 4; ++r) {
            const int m = m0 + wr + (lane >> 4) * 4 + r;
            const int n = wc + nt * 16 + (lane & 15);
            logits[(size_t)m * NEXP + n] = acc[nt][r];
        }
    }
}

// ---------------------------------------------------------------------------
// Kernel 2: per-token top-CAND candidates from approx logits. One wave/token.
// ---------------------------------------------------------------------------
__global__ __launch_bounds__(256)
void topk_cand(const float* __restrict__ logits, int* __restrict__ cand) {
    const int lane  = threadIdx.x & 63;
    const int token = blockIdx.x * 4 + (threadIdx.x >> 6);
    const float* lp = logits + (size_t)token * NEXP;

    float s[4];
    #pragma unroll
    for (int j = 0; j < 4; ++j) s[j] = lp[j * 64 + lane];

    int mye = 0;
    #pragma unroll
    for (int r = 0; r < CAND; ++r) {
        float bv = s[0];
        int   be = lane;
        #pragma unroll
        for (int j = 1; j < 4; ++j) {
            if (s[j] > bv) { bv = s[j]; be = j * 64 + lane; }
        }
        #pragma unroll
        for (int off = 32; off > 0; off >>= 1) {
            const float ov = __shfl_xor(bv, off, 64);
            const int   oe = __shfl_xor(be, off, 64);
            if (ov > bv || (ov == bv && oe < be)) { bv = ov; be = oe; }
        }
        if (lane == r) mye = be;
        if ((be & 63) == lane) s[be >> 6] = -1e30f;
    }

    if (lane < CAND) cand[token * CAND + lane] = mye;
}

// ---------------------------------------------------------------------------
// Kernel 3: fp64 rescore, NO butterflies. Per-token block (256 thr).
// Wave w does candidates w, w+4, w+8; lane partials -> LDS; 12 threads reduce
// 64 partials each (ILP-4); lane 0 serial top-8 over 12 fp64 logits;
// fp32 sigmoid + normalize lane-parallel.
// ---------------------------------------------------------------------------
__global__ __launch_bounds__(256)
void rescore(const float* __restrict__ x, const float* __restrict__ w,
             const int* __restrict__ cand, float* __restrict__ out) {
    __shared__ float  xs[DIM];            // 16 KB
    __shared__ double part[CAND][65];     // padded: reducer threads hit distinct banks
    __shared__ double totv[CAND];
    __shared__ int    ce[CAND];
    __shared__ double sel_v[TOPK];
    __shared__ int    sel_i[TOPK];
    __shared__ float  sig[TOPK];

    const int t = threadIdx.x, wave = t >> 6, lane = t & 63;
    const int token = blockIdx.x;

    const float4* xp4 = (const float4*)(x + (size_t)token * DIM);
    #pragma unroll
    for (int i = 0; i < 4; ++i)
        *(float4*)&xs[(t + i * 256) * 4] = xp4[t + i * 256];
    if (t < CAND) ce[t] = cand[token * CAND + t];
    __syncthreads();

    for (int c = wave; c < CAND; c += 4) {
        const float4* wp4 = (const float4*)(w + (size_t)ce[c] * DIM);
        double a0 = 0.0, a1 = 0.0, a2 = 0.0, a3 = 0.0;
        #pragma unroll
        for (int i = 0; i < 16; ++i) {
            const float4 wv = wp4[lane + i * 64];
            const float4 xv = *(const float4*)&xs[(lane + i * 64) * 4];
            a0 = fma((double)xv.x, (double)wv.x, a0);
            a1 = fma((double)xv.y, (double)wv.y, a1);
            a2 = fma((double)xv.z, (double)wv.z, a2);
            a3 = fma((double)xv.w, (double)wv.w, a3);
        }
        part[c][lane] = (a0 + a1) + (a2 + a3);
    }
    __syncthreads();

    if (wave == 0) {
        // 12 reducer threads, 4 ILP chains each
        if (lane < CAND) {
            double s0 = 0.0, s1 = 0.0, s2 = 0.0, s3 = 0.0;
            #pragma unroll
            for (int i = 0; i < 16; ++i) {
                s0 += part[lane][4 * i + 0];
                s1 += part[lane][4 * i + 1];
                s2 += part[lane][4 * i + 2];
                s3 += part[lane][4 * i + 3];
            }
            totv[lane] = (s0 + s1) + (s2 + s3);
        }
        // lane 0: serial exact top-8 (value desc, index asc) over 12 fp64 logits
        if (lane == 0) {
            double v[CAND]; int ei[CAND];
            #pragma unroll
            for (int i = 0; i < CAND; ++i) { v[i] = totv[i]; ei[i] = ce[i]; }
            #pragma unroll
            for (int r = 0; r < TOPK; ++r) {
                int b = 0;
                #pragma unroll
                for (int i = 1; i < CAND; ++i) {
                    if (v[i] > v[b] || (v[i] == v[b] && ei[i] < ei[b])) b = i;
                }
                sel_v[r] = v[b]; sel_i[r] = ei[b];
                v[b] = -1.0e300;
            }
        }
        // lanes 0-7: fp32 sigmoid + normalize (wave-lockstep LDS visibility)
        if (lane < TOPK) {
            const float sg = 1.0f / (1.0f + expf(-(float)sel_v[lane]));
            sig[lane] = sg;
        }
        if (lane < TOPK) {
            float sum = 0.f;
            #pragma unroll
            for (int i = 0; i < TOPK; ++i) sum += sig[i];
            out[(size_t)token * TOPK + lane] = sig[lane] / sum;
            out[(size_t)TOKENS * TOPK + (size_t)token * TOPK + lane] = (float)sel_i[lane];
        }
    }
}

extern "C" void kernel_launch(void* const* d_in, const int* in_sizes, int n_in,
                              void* d_out, int out_size, void* d_ws, size_t ws_size,
                              hipStream_t stream) {
    const float* x = (const float*)d_in[0];   // [8192, 4096]
    const float* w = (const float*)d_in[1];   // [256, 4096]
    float* out     = (float*)d_out;           // 65536 gates + 65536 idx-as-float

    // ws layout: logits fp32 (8 MB) | cand (384 KB) | wh fp16 (2 MB)
    float*     logits = (float*)d_ws;
    int*       candp  = (int*)((char*)d_ws + (size_t)TOKENS * NEXP * sizeof(float));
    _Float16*  wh     = (_Float16*)((char*)d_ws + (size_t)TOKENS * NEXP * sizeof(float)
                                                + (size_t)TOKENS * CAND * sizeof(int));

    convert_w<<<256, 256, 0, stream>>>(w, wh);
    gemm_fp16<<<TOKENS / MT, 512, 0, stream>>>(x, wh, logits);
    topk_cand<<<TOKENS / 4, 256, 0, stream>>>(logits, candp);
    rescore<<<TOKENS, 256, 0, stream>>>(x, w, candp, out);
}

// Round 5
// 381.183 us; speedup vs baseline: 2.8263x; 1.3732x over previous
//
#include <hip/hip_runtime.h>
#include <hip/hip_bf16.h>
#include <hip/hip_fp16.h>
#include <math.h>

// Problem constants
#define TOKENS   8192
#define DIM      4096
#define NEXP     256
#define TOPK     8
#define CAND     12      // fp16-GEMM candidates refined in fp64

// GEMM tiling
#define MT   32          // token rows per block
#define BK   64          // k-chunk
#define LDH  72          // padded LDS row stride in halves (144 B, 16B-aligned)

typedef _Float16 f16x8 __attribute__((ext_vector_type(8)));
typedef _Float16 f16x4 __attribute__((ext_vector_type(4)));
typedef float    f32x4 __attribute__((ext_vector_type(4)));

// ---------------------------------------------------------------------------
// Kernel 0: W fp32 -> fp16 (1M elems, one-shot)
// ---------------------------------------------------------------------------
__global__ __launch_bounds__(256)
void convert_w(const float* __restrict__ w, _Float16* __restrict__ wh) {
    const int t = blockIdx.x * 256 + threadIdx.x;
    const float4* wp = (const float4*)w;
    f16x8* op = (f16x8*)wh;
    #pragma unroll
    for (int i = 0; i < 2; ++i) {
        const int o = i * 65536 + t;
        const float4 a = wp[2 * o];
        const float4 b = wp[2 * o + 1];
        f16x8 h;
        h[0] = (_Float16)a.x; h[1] = (_Float16)a.y;
        h[2] = (_Float16)a.z; h[3] = (_Float16)a.w;
        h[4] = (_Float16)b.x; h[5] = (_Float16)b.y;
        h[6] = (_Float16)b.z; h[7] = (_Float16)b.w;
        op[o] = h;
    }
}

// ---------------------------------------------------------------------------
// Kernel 1: partial logits = x @ W^T via fp16 MFMA, K-split across blockIdx.y.
// Each block: MT=32 tokens x 256 experts over kspan of K. 512 thr = 8 waves,
// wave-tile 16x128. K-split gives 256*S blocks -> 3+ blocks/CU so other
// blocks' MFMA covers the 1-iteration prefetch distance.
// ---------------------------------------------------------------------------
__global__ __launch_bounds__(512)
void gemm_fp16(const float* __restrict__ x, const _Float16* __restrict__ wh,
               float* __restrict__ logits, int kspan) {
    __shared__ _Float16 ah[MT][LDH];      // 4.6 KB
    __shared__ _Float16 bh[NEXP][LDH];    // 36.9 KB

    const int t    = threadIdx.x;
    const int wave = t >> 6, lane = t & 63;
    const int m0   = blockIdx.x * MT;
    const int kb   = blockIdx.y * kspan;
    float* lp      = logits + (size_t)blockIdx.y * TOKENS * NEXP;

    const int wr   = (wave >> 2) * 16;    // wave row offset (0|16)
    const int wc   = (wave & 3) * 64;     // wave col offset (0..192)

    const int ar = t >> 4, ak = (t & 15) * 4;   // A stage: float4
    const int br = t >> 3, bk = (t & 7) * 8;    // B stage: f16x8

    const int fm = lane & 15;
    const int fk = (lane >> 4) * 8;

    f32x4 acc[4];
    #pragma unroll
    for (int nt = 0; nt < 4; ++nt) acc[nt] = (f32x4){0.f, 0.f, 0.f, 0.f};

    // prefetch first chunk
    float4 xa = *(const float4*)(x + (size_t)(m0 + ar) * DIM + kb + ak);
    f16x8 wb[4];
    #pragma unroll
    for (int c = 0; c < 4; ++c)
        wb[c] = *(const f16x8*)(wh + (size_t)(c * 64 + br) * DIM + kb + bk);

    for (int k0 = kb; k0 < kb + kspan; k0 += BK) {
        f16x4 hx;
        hx[0] = (_Float16)xa.x; hx[1] = (_Float16)xa.y;
        hx[2] = (_Float16)xa.z; hx[3] = (_Float16)xa.w;
        *(f16x4*)&ah[ar][ak] = hx;
        #pragma unroll
        for (int c = 0; c < 4; ++c)
            *(f16x8*)&bh[c * 64 + br][bk] = wb[c];
        __syncthreads();

        if (k0 + BK < kb + kspan) {
            xa = *(const float4*)(x + (size_t)(m0 + ar) * DIM + k0 + BK + ak);
            #pragma unroll
            for (int c = 0; c < 4; ++c)
                wb[c] = *(const f16x8*)(wh + (size_t)(c * 64 + br) * DIM + k0 + BK + bk);
        }

        #pragma unroll
        for (int kk = 0; kk < 2; ++kk) {
            const f16x8 af = *(const f16x8*)&ah[wr + fm][kk * 32 + fk];
            #pragma unroll
            for (int nt = 0; nt < 4; ++nt) {
                const f16x8 bf = *(const f16x8*)&bh[wc + nt * 16 + fm][kk * 32 + fk];
                acc[nt] = __builtin_amdgcn_mfma_f32_16x16x32_f16(af, bf, acc[nt], 0, 0, 0);
            }
        }
        __syncthreads();
    }

    // epilogue: C/D layout col=lane&15, row=(lane>>4)*4+reg  [m89/m91]
    #pragma unroll
    for (int nt = 0; nt < 4; ++nt) {
        #pragma unroll
        for (int r = 0; r < 4; ++r) {
            const int m = m0 + wr + (lane >> 4) * 4 + r;
            const int n = wc + nt * 16 + (lane & 15);
            lp[(size_t)m * NEXP + n] = acc[nt][r];
        }
    }
}

// ---------------------------------------------------------------------------
// Kernel 2: sum K-split planes, per-token top-CAND candidates. One wave/token.
// ---------------------------------------------------------------------------
__global__ __launch_bounds__(256)
void topk_cand(const float* __restrict__ logits, int* __restrict__ cand,
               int nsplit) {
    const int lane  = threadIdx.x & 63;
    const int token = blockIdx.x * 4 + (threadIdx.x >> 6);
    const float* lp = logits + (size_t)token * NEXP;

    float s[4];
    #pragma unroll
    for (int j = 0; j < 4; ++j) s[j] = 0.f;
    for (int p = 0; p < nsplit; ++p) {
        const float* pp = lp + (size_t)p * TOKENS * NEXP;
        #pragma unroll
        for (int j = 0; j < 4; ++j) s[j] += pp[j * 64 + lane];
    }

    int mye = 0;
    #pragma unroll
    for (int r = 0; r < CAND; ++r) {
        float bv = s[0];
        int   be = lane;
        #pragma unroll
        for (int j = 1; j < 4; ++j) {
            if (s[j] > bv) { bv = s[j]; be = j * 64 + lane; }
        }
        #pragma unroll
        for (int off = 32; off > 0; off >>= 1) {
            const float ov = __shfl_xor(bv, off, 64);
            const int   oe = __shfl_xor(be, off, 64);
            if (ov > bv || (ov == bv && oe < be)) { bv = ov; be = oe; }
        }
        if (lane == r) mye = be;
        if ((be & 63) == lane) s[be >> 6] = -1e30f;
    }

    if (lane < CAND) cand[token * CAND + lane] = mye;
}

// ---------------------------------------------------------------------------
// Kernel 3: fp64 rescore — pure per-wave streaming. No LDS, no barriers.
// One wave per token (4 waves/block). 3 passes x 4 candidates; 16 independent
// fp64 chains per pass; rank-counting selection (no dynamic indexing, no
// butarg shuffle-argmax). x read per pass (L1/L2-hot after pass 1).
// ---------------------------------------------------------------------------
__global__ __launch_bounds__(256)
void rescore(const float* __restrict__ x, const float* __restrict__ w,
             const int* __restrict__ cand, float* __restrict__ out) {
    const int wave = threadIdx.x >> 6, lane = threadIdx.x & 63;
    const int token = blockIdx.x * 4 + wave;

    const float4* xp4 = (const float4*)(x + (size_t)token * DIM);

    int ce[CAND];
    #pragma unroll
    for (int c = 0; c < CAND; ++c) ce[c] = cand[token * CAND + c];

    double tot[CAND];

    #pragma unroll
    for (int g = 0; g < 3; ++g) {
        const float4* wp0 = (const float4*)(w + (size_t)ce[g * 4 + 0] * DIM);
        const float4* wp1 = (const float4*)(w + (size_t)ce[g * 4 + 1] * DIM);
        const float4* wp2 = (const float4*)(w + (size_t)ce[g * 4 + 2] * DIM);
        const float4* wp3 = (const float4*)(w + (size_t)ce[g * 4 + 3] * DIM);

        double a0x=0,a0y=0,a0z=0,a0w=0, a1x=0,a1y=0,a1z=0,a1w=0;
        double a2x=0,a2y=0,a2z=0,a2w=0, a3x=0,a3y=0,a3z=0,a3w=0;

        #pragma unroll 4
        for (int i = 0; i < 16; ++i) {
            const int o = lane + i * 64;
            const float4 xv = xp4[o];
            const float4 w0 = wp0[o];
            const float4 w1 = wp1[o];
            const float4 w2 = wp2[o];
            const float4 w3 = wp3[o];
            a0x = fma((double)xv.x, (double)w0.x, a0x);
            a0y = fma((double)xv.y, (double)w0.y, a0y);
            a0z = fma((double)xv.z, (double)w0.z, a0z);
            a0w = fma((double)xv.w, (double)w0.w, a0w);
            a1x = fma((double)xv.x, (double)w1.x, a1x);
            a1y = fma((double)xv.y, (double)w1.y, a1y);
            a1z = fma((double)xv.z, (double)w1.z, a1z);
            a1w = fma((double)xv.w, (double)w1.w, a1w);
            a2x = fma((double)xv.x, (double)w2.x, a2x);
            a2y = fma((double)xv.y, (double)w2.y, a2y);
            a2z = fma((double)xv.z, (double)w2.z, a2z);
            a2w = fma((double)xv.w, (double)w2.w, a2w);
            a3x = fma((double)xv.x, (double)w3.x, a3x);
            a3y = fma((double)xv.y, (double)w3.y, a3y);
            a3z = fma((double)xv.z, (double)w3.z, a3z);
            a3w = fma((double)xv.w, (double)w3.w, a3w);
        }
        tot[g * 4 + 0] = (a0x + a0y) + (a0z + a0w);
        tot[g * 4 + 1] = (a1x + a1y) + (a1z + a1w);
        tot[g * 4 + 2] = (a2x + a2y) + (a2z + a2w);
        tot[g * 4 + 3] = (a3x + a3y) + (a3z + a3w);
    }

    // 12 independent fp64 butterflies (interleaved by the scheduler)
    #pragma unroll
    for (int off = 32; off > 0; off >>= 1) {
        #pragma unroll
        for (int c = 0; c < CAND; ++c)
            tot[c] += __shfl_xor(tot[c], off, 64);
    }

    // rank-counting selection: fully static indexing
    int rank[CAND];
    #pragma unroll
    for (int c = 0; c < CAND; ++c) {
        int r = 0;
        #pragma unroll
        for (int j = 0; j < CAND; ++j) {
            if (j == c) continue;
            if (tot[j] > tot[c] || (tot[j] == tot[c] && ce[j] < ce[c])) ++r;
        }
        rank[c] = r;
    }

    float sig[CAND];
    float sum = 0.f;
    #pragma unroll
    for (int c = 0; c < CAND; ++c) {
        sig[c] = 1.0f / (1.0f + expf(-(float)tot[c]));
        if (rank[c] < TOPK) sum += sig[c];
    }

    if (lane < TOPK) {
        float g = 0.f; int ei = 0;
        #pragma unroll
        for (int c = 0; c < CAND; ++c)
            if (rank[c] == lane) { g = sig[c]; ei = ce[c]; }
        out[(size_t)token * TOPK + lane] = g / sum;
        out[(size_t)TOKENS * TOPK + (size_t)token * TOPK + lane] = (float)ei;
    }
}

extern "C" void kernel_launch(void* const* d_in, const int* in_sizes, int n_in,
                              void* d_out, int out_size, void* d_ws, size_t ws_size,
                              hipStream_t stream) {
    const float* x = (const float*)d_in[0];   // [8192, 4096]
    const float* w = (const float*)d_in[1];   // [256, 4096]
    float* out     = (float*)d_out;           // 65536 gates + 65536 idx-as-float

    const size_t plane = (size_t)TOKENS * NEXP * sizeof(float);   // 8 MB
    const size_t fixed = (size_t)TOKENS * CAND * sizeof(int)      // cand
                       + (size_t)NEXP * DIM * sizeof(_Float16);   // wh
    int S = 4;
    if (ws_size < 4 * plane + fixed) S = (ws_size >= 2 * plane + fixed) ? 2 : 1;

    float*     logits = (float*)d_ws;
    int*       candp  = (int*)((char*)d_ws + (size_t)S * plane);
    _Float16*  wh     = (_Float16*)((char*)candp + (size_t)TOKENS * CAND * sizeof(int));

    convert_w<<<256, 256, 0, stream>>>(w, wh);
    dim3 ggrid(TOKENS / MT, S);
    gemm_fp16<<<ggrid, 512, 0, stream>>>(x, wh, logits, DIM / S);
    topk_cand<<<TOKENS / 4, 256, 0, stream>>>(logits, candp, S);
    rescore<<<TOKENS / 4, 256, 0, stream>>>(x, w, candp, out);
}

// Round 6
// 358.362 us; speedup vs baseline: 3.0063x; 1.0637x over previous
//
#include <hip/hip_runtime.h>
#include <hip/hip_bf16.h>
#include <hip/hip_fp16.h>
#include <math.h>

// Problem constants
#define TOKENS   8192
#define DIM      4096
#define NEXP     256
#define TOPK     8
#define CAND     12

// GEMM v3 tiling
#define MT3      128               // tokens per block
#define BK3      64                // k per staged chunk
#define KG       (DIM / 32)        // 128 k-fragment-groups in W

typedef _Float16 f16x8 __attribute__((ext_vector_type(8)));
typedef _Float16 f16x4 __attribute__((ext_vector_type(4)));
typedef float    f32x4 __attribute__((ext_vector_type(4)));

typedef const __attribute__((address_space(1))) unsigned int* gas_ptr;
typedef       __attribute__((address_space(3))) unsigned int* las_ptr;

// ---------------------------------------------------------------------------
// Kernel 0: W fp32 -> fp16 in MFMA-B-fragment-swizzled order.
// whs is a sequence of 1 KB tiles, tile index = ng*KG + kg covering experts
// [ng*16,+16) x k [kg*32,+32). Within a tile, chunk c = q*16 + r (16 B) holds
// B[n=ng*16+r][k=kg*32+q*8 .. +8] — exactly lane c's mfma_16x16x32 B-fragment.
// ---------------------------------------------------------------------------
__global__ __launch_bounds__(256)
void convert_w(const float* __restrict__ w, _Float16* __restrict__ whs) {
    const int g = blockIdx.x * 256 + threadIdx.x;   // chunk id, 131072 total
    const int tile = g >> 6, c = g & 63;
    const int q = c >> 4, r = c & 15;
    const int ng = tile / KG, kg = tile % KG;
    const int n = ng * 16 + r, k = kg * 32 + q * 8;
    const float4 a = *(const float4*)(w + (size_t)n * DIM + k);
    const float4 b = *(const float4*)(w + (size_t)n * DIM + k + 4);
    f16x8 h;
    h[0] = (_Float16)a.x; h[1] = (_Float16)a.y;
    h[2] = (_Float16)a.z; h[3] = (_Float16)a.w;
    h[4] = (_Float16)b.x; h[5] = (_Float16)b.y;
    h[6] = (_Float16)b.z; h[7] = (_Float16)b.w;
    *(f16x8*)(whs + (size_t)g * 8) = h;             // coalesced 16 B writes
}

// ---------------------------------------------------------------------------
// Kernel 1: partial logits via fp16 MFMA, K-split over blockIdx.y.
// Block: 128 tokens x 256 experts, 512 thr = 8 waves, wave-tile 64x64
// (4x4 of 16x16x32 => 16 MFMA per 8 KB LDS reads -> ~31% LDS-BW ceiling).
// B staged by global_load_lds width=16 from pre-swizzled whs (frag order,
// conflict-free). A staged from fp32 x with on-the-fly cvt into frag order.
// ---------------------------------------------------------------------------
__global__ __launch_bounds__(512, 2)
void gemm_v3(const float* __restrict__ x, const _Float16* __restrict__ whs,
             float* __restrict__ logits, int kspan) {
    __shared__ _Float16 As[16 * 512];   // 16 tiles x 1 KB = 16 KB
    __shared__ _Float16 Bs[32 * 512];   // 32 tiles x 1 KB = 32 KB

    const int t = threadIdx.x, w = t >> 6, lane = t & 63;
    const int m0 = blockIdx.x * MT3;
    const int kb = blockIdx.y * kspan;
    float* lp    = logits + (size_t)blockIdx.y * TOKENS * NEXP;

    const int rg = w >> 2;              // wave row-group (0..1): 64 tokens
    const int cg = w & 3;               // wave col-group (0..3): 64 experts

    // A staging decode: thread t handles chunks (am, ack) and (am, ack+1)
    const int am  = t >> 2;             // token row 0..127
    const int ack = (t & 3) * 2;        // k-chunk (8 halves each) 0,2,4,6
    const int amg = am >> 4, amr = am & 15;
    // LDS half-offsets of the two A chunks
    const int aoff0 = ((amg * 2 + (ack >> 2)) * 64 + (ack & 3) * 16 + amr) * 8;
    const int ack1  = ack + 1;
    const int aoff1 = ((amg * 2 + (ack1 >> 2)) * 64 + (ack1 & 3) * 16 + amr) * 8;

    f32x4 acc[4][4];
    #pragma unroll
    for (int i = 0; i < 4; ++i)
        #pragma unroll
        for (int j = 0; j < 4; ++j) acc[i][j] = (f32x4){0.f, 0.f, 0.f, 0.f};

    // preload x regs for iter 0 (16 fp32 per thread = row am, k [ack*8, +16))
    const float* xrow = x + (size_t)(m0 + am) * DIM + ack * 8;
    float4 xr0 = *(const float4*)(xrow + kb);
    float4 xr1 = *(const float4*)(xrow + kb + 4);
    float4 xr2 = *(const float4*)(xrow + kb + 8);
    float4 xr3 = *(const float4*)(xrow + kb + 12);

    for (int k0 = kb; k0 < kb + kspan; k0 += BK3) {
        // B DMA: wave w stages tiles ti = w*4 .. w*4+3 (ng = ti>>1, kgl = ti&1)
        #pragma unroll
        for (int c = 0; c < 4; ++c) {
            const int ti  = w * 4 + c;
            const int ng  = ti >> 1, kgl = ti & 1;
            const _Float16* gp = whs + ((size_t)(ng * KG + (k0 >> 5) + kgl)) * 512
                                     + lane * 8;
            __builtin_amdgcn_global_load_lds((gas_ptr)gp, (las_ptr)&Bs[ti * 512],
                                             16, 0, 0);
        }
        // A cvt + frag-order ds_write
        {
            f16x8 h0, h1;
            h0[0] = (_Float16)xr0.x; h0[1] = (_Float16)xr0.y;
            h0[2] = (_Float16)xr0.z; h0[3] = (_Float16)xr0.w;
            h0[4] = (_Float16)xr1.x; h0[5] = (_Float16)xr1.y;
            h0[6] = (_Float16)xr1.z; h0[7] = (_Float16)xr1.w;
            h1[0] = (_Float16)xr2.x; h1[1] = (_Float16)xr2.y;
            h1[2] = (_Float16)xr2.z; h1[3] = (_Float16)xr2.w;
            h1[4] = (_Float16)xr3.x; h1[5] = (_Float16)xr3.y;
            h1[6] = (_Float16)xr3.z; h1[7] = (_Float16)xr3.w;
            *(f16x8*)&As[aoff0] = h0;
            *(f16x8*)&As[aoff1] = h1;
        }
        __syncthreads();   // drains DMA (vmcnt) + ds_writes (lgkm)

        // prefetch next chunk's x into regs (overlaps MFMA)
        if (k0 + BK3 < kb + kspan) {
            xr0 = *(const float4*)(xrow + k0 + BK3);
            xr1 = *(const float4*)(xrow + k0 + BK3 + 4);
            xr2 = *(const float4*)(xrow + k0 + BK3 + 8);
            xr3 = *(const float4*)(xrow + k0 + BK3 + 12);
        }

        #pragma unroll
        for (int kk = 0; kk < 2; ++kk) {
            f16x8 af[4], bf[4];
            #pragma unroll
            for (int mt = 0; mt < 4; ++mt)
                af[mt] = *(const f16x8*)&As[(((rg * 4 + mt) * 2 + kk) * 64 + lane) * 8];
            #pragma unroll
            for (int nt = 0; nt < 4; ++nt)
                bf[nt] = *(const f16x8*)&Bs[(((cg * 4 + nt) * 2 + kk) * 64 + lane) * 8];
            #pragma unroll
            for (int mt = 0; mt < 4; ++mt)
                #pragma unroll
                for (int nt = 0; nt < 4; ++nt)
                    acc[mt][nt] = __builtin_amdgcn_mfma_f32_16x16x32_f16(
                        af[mt], bf[nt], acc[mt][nt], 0, 0, 0);
        }
        __syncthreads();
    }

    // epilogue: C/D layout col=lane&15, row=(lane>>4)*4+reg
    #pragma unroll
    for (int mt = 0; mt < 4; ++mt) {
        #pragma unroll
        for (int nt = 0; nt < 4; ++nt) {
            #pragma unroll
            for (int r = 0; r < 4; ++r) {
                const int m = m0 + (rg * 4 + mt) * 16 + (lane >> 4) * 4 + r;
                const int n = (cg * 4 + nt) * 16 + (lane & 15);
                lp[(size_t)m * NEXP + n] = acc[mt][nt][r];
            }
        }
    }
}

// ---------------------------------------------------------------------------
// Kernel 2: sum K-split planes, per-token top-CAND candidates. One wave/token.
// ---------------------------------------------------------------------------
__global__ __launch_bounds__(256)
void topk_cand(const float* __restrict__ logits, int* __restrict__ cand,
               int nsplit) {
    const int lane  = threadIdx.x & 63;
    const int token = blockIdx.x * 4 + (threadIdx.x >> 6);
    const float* lp = logits + (size_t)token * NEXP;

    float s[4];
    #pragma unroll
    for (int j = 0; j < 4; ++j) s[j] = 0.f;
    for (int p = 0; p < nsplit; ++p) {
        const float* pp = lp + (size_t)p * TOKENS * NEXP;
        #pragma unroll
        for (int j = 0; j < 4; ++j) s[j] += pp[j * 64 + lane];
    }

    int mye = 0;
    #pragma unroll
    for (int r = 0; r < CAND; ++r) {
        float bv = s[0];
        int   be = lane;
        #pragma unroll
        for (int j = 1; j < 4; ++j) {
            if (s[j] > bv) { bv = s[j]; be = j * 64 + lane; }
        }
        #pragma unroll
        for (int off = 32; off > 0; off >>= 1) {
            const float ov = __shfl_xor(bv, off, 64);
            const int   oe = __shfl_xor(be, off, 64);
            if (ov > bv || (ov == bv && oe < be)) { bv = ov; be = oe; }
        }
        if (lane == r) mye = be;
        if ((be & 63) == lane) s[be >> 6] = -1e30f;
    }

    if (lane < CAND) cand[token * CAND + lane] = mye;
}

// ---------------------------------------------------------------------------
// Kernel 3: fp64 rescore — SINGLE pass over x for all 12 candidates.
// One wave/token. W bases scalarized (readfirstlane -> saddr loads).
// 24 fp64 accumulator chains; rank-counting selection (round-4, verified).
// ---------------------------------------------------------------------------
__global__ __launch_bounds__(256)
void rescore(const float* __restrict__ x, const float* __restrict__ w,
             const int* __restrict__ cand, float* __restrict__ out) {
    const int wave = threadIdx.x >> 6, lane = threadIdx.x & 63;
    const int token = blockIdx.x * 4 + wave;

    const float4* xp4 = (const float4*)(x + (size_t)token * DIM);

    int ce[CAND];
    const float4* wp[CAND];
    #pragma unroll
    for (int c = 0; c < CAND; ++c) {
        ce[c] = __builtin_amdgcn_readfirstlane(cand[token * CAND + c]);
        wp[c] = (const float4*)(w + (size_t)ce[c] * DIM);
    }

    double acc[2 * CAND];
    #pragma unroll
    for (int c = 0; c < 2 * CAND; ++c) acc[c] = 0.0;

    #pragma unroll 2
    for (int i = 0; i < 16; ++i) {
        const int o = lane + i * 64;
        const float4 xv = xp4[o];
        const double dx = (double)xv.x, dy = (double)xv.y;
        const double dz = (double)xv.z, dw = (double)xv.w;
        #pragma unroll
        for (int c = 0; c < CAND; ++c) {
            const float4 wv = wp[c][o];
            double e = fma(dx, (double)wv.x, acc[2 * c]);
            acc[2 * c] = fma(dy, (double)wv.y, e);
            double f = fma(dz, (double)wv.z, acc[2 * c + 1]);
            acc[2 * c + 1] = fma(dw, (double)wv.w, f);
        }
    }

    double tot[CAND];
    #pragma unroll
    for (int c = 0; c < CAND; ++c) tot[c] = acc[2 * c] + acc[2 * c + 1];

    #pragma unroll
    for (int off = 32; off > 0; off >>= 1) {
        #pragma unroll
        for (int c = 0; c < CAND; ++c)
            tot[c] += __shfl_xor(tot[c], off, 64);
    }

    int rank[CAND];
    #pragma unroll
    for (int c = 0; c < CAND; ++c) {
        int r = 0;
        #pragma unroll
        for (int j = 0; j < CAND; ++j) {
            if (j == c) continue;
            if (tot[j] > tot[c] || (tot[j] == tot[c] && ce[j] < ce[c])) ++r;
        }
        rank[c] = r;
    }

    float sig[CAND];
    float sum = 0.f;
    #pragma unroll
    for (int c = 0; c < CAND; ++c) {
        sig[c] = 1.0f / (1.0f + expf(-(float)tot[c]));
        if (rank[c] < TOPK) sum += sig[c];
    }

    if (lane < TOPK) {
        float g = 0.f; int ei = 0;
        #pragma unroll
        for (int c = 0; c < CAND; ++c)
            if (rank[c] == lane) { g = sig[c]; ei = ce[c]; }
        out[(size_t)token * TOPK + lane] = g / sum;
        out[(size_t)TOKENS * TOPK + (size_t)token * TOPK + lane] = (float)ei;
    }
}

extern "C" void kernel_launch(void* const* d_in, const int* in_sizes, int n_in,
                              void* d_out, int out_size, void* d_ws, size_t ws_size,
                              hipStream_t stream) {
    const float* x = (const float*)d_in[0];   // [8192, 4096]
    const float* w = (const float*)d_in[1];   // [256, 4096]
    float* out     = (float*)d_out;

    const size_t plane = (size_t)TOKENS * NEXP * sizeof(float);   // 8 MB
    const size_t fixed = (size_t)TOKENS * CAND * sizeof(int)
                       + (size_t)NEXP * DIM * sizeof(_Float16);
    int S = 4;
    if (ws_size < 4 * plane + fixed) S = (ws_size >= 2 * plane + fixed) ? 2 : 1;

    float*     logits = (float*)d_ws;
    int*       candp  = (int*)((char*)d_ws + (size_t)S * plane);
    _Float16*  whs    = (_Float16*)((char*)candp + (size_t)TOKENS * CAND * sizeof(int));

    convert_w<<<512, 256, 0, stream>>>(w, whs);
    dim3 ggrid(TOKENS / MT3, S);
    gemm_v3<<<ggrid, 512, 0, stream>>>(x, whs, logits, DIM / S);
    topk_cand<<<TOKENS / 4, 256, 0, stream>>>(logits, candp, S);
    rescore<<<TOKENS / 4, 256, 0, stream>>>(x, w, candp, out);
}

// Round 7
// 318.683 us; speedup vs baseline: 3.3806x; 1.1245x over previous
//
#include <hip/hip_runtime.h>
#include <hip/hip_bf16.h>
#include <hip/hip_fp16.h>
#include <math.h>

// Problem constants
#define TOKENS   8192
#define DIM      4096
#define NEXP     256
#define TOPK     8
#define CAND     12

// GEMM tiling
#define MT4      64                // tokens per block
#define BK3      64                // k per staged chunk
#define KG       (DIM / 32)        // 128 k-fragment-groups in W

typedef _Float16 f16x8 __attribute__((ext_vector_type(8)));
typedef float    f32x4 __attribute__((ext_vector_type(4)));

typedef const __attribute__((address_space(1))) unsigned int* gas_ptr;
typedef       __attribute__((address_space(3))) unsigned int* las_ptr;

// ---------------------------------------------------------------------------
// Kernel 0: W fp32 -> fp16 in MFMA-B-fragment-swizzled order.
// 1 KB tiles, tile = ng*KG + kg covers experts [ng*16,+16) x k [kg*32,+32);
// chunk c = q*16+r holds B[n=ng*16+r][k=kg*32+q*8..+8] = lane c's B-fragment.
// ---------------------------------------------------------------------------
__global__ __launch_bounds__(256)
void convert_w(const float* __restrict__ w, _Float16* __restrict__ whs) {
    const int g = blockIdx.x * 256 + threadIdx.x;   // chunk id, 131072 total
    const int tile = g >> 6, c = g & 63;
    const int q = c >> 4, r = c & 15;
    const int ng = tile / KG, kg = tile % KG;
    const int n = ng * 16 + r, k = kg * 32 + q * 8;
    const float4 a = *(const float4*)(w + (size_t)n * DIM + k);
    const float4 b = *(const float4*)(w + (size_t)n * DIM + k + 4);
    f16x8 h;
    h[0] = (_Float16)a.x; h[1] = (_Float16)a.y;
    h[2] = (_Float16)a.z; h[3] = (_Float16)a.w;
    h[4] = (_Float16)b.x; h[5] = (_Float16)b.y;
    h[6] = (_Float16)b.z; h[7] = (_Float16)b.w;
    *(f16x8*)(whs + (size_t)g * 8) = h;
}

// ---------------------------------------------------------------------------
// Kernel 1: partial logits via fp16 MFMA, K-split over blockIdx.y.
// Block: 64 tokens x 256 experts, 256 thr = 4 waves, wave-tile 64x64
// (16 MFMA / 8KB LDS-read). LDS 40 KB -> 3 blocks/CU; grid 128*S blocks.
// B staged via global_load_lds(16B) from pre-swizzled whs; A cvt'd on the fly.
// ---------------------------------------------------------------------------
__global__ __launch_bounds__(256, 3)
void gemm_v4(const float* __restrict__ x, const _Float16* __restrict__ whs,
             float* __restrict__ logits, int kspan) {
    __shared__ _Float16 As[8 * 512];    //  8 tiles x 1 KB = 8 KB
    __shared__ _Float16 Bs[32 * 512];   // 32 tiles x 1 KB = 32 KB

    const int t = threadIdx.x, w = t >> 6, lane = t & 63;
    const int m0 = blockIdx.x * MT4;
    const int kb = blockIdx.y * kspan;
    float* lp    = logits + (size_t)blockIdx.y * TOKENS * NEXP;

    // A staging: thread t -> row am (0..63), k-chunks ack, ack+1 (8 halves ea)
    const int am  = t >> 2;
    const int ack = (t & 3) * 2;
    const int amg = am >> 4, amr = am & 15;
    const int aoff0 = ((amg * 2 + (ack >> 2)) * 64 + (ack & 3) * 16 + amr) * 8;
    const int ack1  = ack + 1;
    const int aoff1 = ((amg * 2 + (ack1 >> 2)) * 64 + (ack1 & 3) * 16 + amr) * 8;

    f32x4 acc[4][4];
    #pragma unroll
    for (int i = 0; i < 4; ++i)
        #pragma unroll
        for (int j = 0; j < 4; ++j) acc[i][j] = (f32x4){0.f, 0.f, 0.f, 0.f};

    const float* xrow = x + (size_t)(m0 + am) * DIM + ack * 8;
    float4 xr0 = *(const float4*)(xrow + kb);
    float4 xr1 = *(const float4*)(xrow + kb + 4);
    float4 xr2 = *(const float4*)(xrow + kb + 8);
    float4 xr3 = *(const float4*)(xrow + kb + 12);

    for (int k0 = kb; k0 < kb + kspan; k0 += BK3) {
        // B DMA: wave w stages tiles ti = w*8 .. w*8+7
        #pragma unroll
        for (int c = 0; c < 8; ++c) {
            const int ti  = w * 8 + c;
            const int ng  = ti >> 1, kgl = ti & 1;
            const _Float16* gp = whs + ((size_t)(ng * KG + (k0 >> 5) + kgl)) * 512
                                     + lane * 8;
            __builtin_amdgcn_global_load_lds((gas_ptr)gp, (las_ptr)&Bs[ti * 512],
                                             16, 0, 0);
        }
        // A cvt + frag-order ds_write
        {
            f16x8 h0, h1;
            h0[0] = (_Float16)xr0.x; h0[1] = (_Float16)xr0.y;
            h0[2] = (_Float16)xr0.z; h0[3] = (_Float16)xr0.w;
            h0[4] = (_Float16)xr1.x; h0[5] = (_Float16)xr1.y;
            h0[6] = (_Float16)xr1.z; h0[7] = (_Float16)xr1.w;
            h1[0] = (_Float16)xr2.x; h1[1] = (_Float16)xr2.y;
            h1[2] = (_Float16)xr2.z; h1[3] = (_Float16)xr2.w;
            h1[4] = (_Float16)xr3.x; h1[5] = (_Float16)xr3.y;
            h1[6] = (_Float16)xr3.z; h1[7] = (_Float16)xr3.w;
            *(f16x8*)&As[aoff0] = h0;
            *(f16x8*)&As[aoff1] = h1;
        }
        __syncthreads();

        if (k0 + BK3 < kb + kspan) {
            xr0 = *(const float4*)(xrow + k0 + BK3);
            xr1 = *(const float4*)(xrow + k0 + BK3 + 4);
            xr2 = *(const float4*)(xrow + k0 + BK3 + 8);
            xr3 = *(const float4*)(xrow + k0 + BK3 + 12);
        }

        #pragma unroll
        for (int kk = 0; kk < 2; ++kk) {
            f16x8 af[4], bf[4];
            #pragma unroll
            for (int mt = 0; mt < 4; ++mt)
                af[mt] = *(const f16x8*)&As[((mt * 2 + kk) * 64 + lane) * 8];
            #pragma unroll
            for (int nt = 0; nt < 4; ++nt)
                bf[nt] = *(const f16x8*)&Bs[(((w * 4 + nt) * 2 + kk) * 64 + lane) * 8];
            #pragma unroll
            for (int mt = 0; mt < 4; ++mt)
                #pragma unroll
                for (int nt = 0; nt < 4; ++nt)
                    acc[mt][nt] = __builtin_amdgcn_mfma_f32_16x16x32_f16(
                        af[mt], bf[nt], acc[mt][nt], 0, 0, 0);
        }
        __syncthreads();
    }

    // epilogue: C/D layout col=lane&15, row=(lane>>4)*4+reg
    #pragma unroll
    for (int mt = 0; mt < 4; ++mt) {
        #pragma unroll
        for (int nt = 0; nt < 4; ++nt) {
            #pragma unroll
            for (int r = 0; r < 4; ++r) {
                const int m = m0 + mt * 16 + (lane >> 4) * 4 + r;
                const int n = (w * 4 + nt) * 16 + (lane & 15);
                lp[(size_t)m * NEXP + n] = acc[mt][nt][r];
            }
        }
    }
}

// ---------------------------------------------------------------------------
// Kernel 2: sum K-split planes, per-token top-CAND candidates. One wave/token.
// ---------------------------------------------------------------------------
__global__ __launch_bounds__(256)
void topk_cand(const float* __restrict__ logits, int* __restrict__ cand,
               int nsplit) {
    const int lane  = threadIdx.x & 63;
    const int token = blockIdx.x * 4 + (threadIdx.x >> 6);
    const float* lp = logits + (size_t)token * NEXP;

    float s[4];
    #pragma unroll
    for (int j = 0; j < 4; ++j) s[j] = 0.f;
    for (int p = 0; p < nsplit; ++p) {
        const float* pp = lp + (size_t)p * TOKENS * NEXP;
        #pragma unroll
        for (int j = 0; j < 4; ++j) s[j] += pp[j * 64 + lane];
    }

    int mye = 0;
    #pragma unroll
    for (int r = 0; r < CAND; ++r) {
        float bv = s[0];
        int   be = lane;
        #pragma unroll
        for (int j = 1; j < 4; ++j) {
            if (s[j] > bv) { bv = s[j]; be = j * 64 + lane; }
        }
        #pragma unroll
        for (int off = 32; off > 0; off >>= 1) {
            const float ov = __shfl_xor(bv, off, 64);
            const int   oe = __shfl_xor(be, off, 64);
            if (ov > bv || (ov == bv && oe < be)) { bv = ov; be = oe; }
        }
        if (lane == r) mye = be;
        if ((be & 63) == lane) s[be >> 6] = -1e30f;
    }

    if (lane < CAND) cand[token * CAND + lane] = mye;
}

// ---------------------------------------------------------------------------
// Kernel 3: fp64 rescore — single x pass, register double-buffer pipeline:
// iter i+1's 13 float4 loads issue while iter i's fp64 math runs (~26 loads
// in flight/wave; fixes round-5 VGPR-starved load serialization @60 VGPRs).
// W bases scalarized (readfirstlane -> saddr). Rank-counting selection.
// ---------------------------------------------------------------------------
__global__ __launch_bounds__(256)
void rescore(const float* __restrict__ x, const float* __restrict__ w,
             const int* __restrict__ cand, float* __restrict__ out) {
    const int wave = threadIdx.x >> 6, lane = threadIdx.x & 63;
    const int token = blockIdx.x * 4 + wave;

    const float4* xp4 = (const float4*)(x + (size_t)token * DIM);

    int ce[CAND];
    const float4* wp[CAND];
    #pragma unroll
    for (int c = 0; c < CAND; ++c) {
        ce[c] = __builtin_amdgcn_readfirstlane(cand[token * CAND + c]);
        wp[c] = (const float4*)(w + (size_t)ce[c] * DIM);
    }

    double acc[2 * CAND];
    #pragma unroll
    for (int c = 0; c < 2 * CAND; ++c) acc[c] = 0.0;

    float4 xb[2], wb[2][CAND];
    xb[0] = xp4[lane];
    #pragma unroll
    for (int c = 0; c < CAND; ++c) wb[0][c] = wp[c][lane];

    #pragma unroll
    for (int i = 0; i < 16; ++i) {
        const int cur = i & 1, nxt = cur ^ 1;
        if (i < 15) {
            const int o = lane + (i + 1) * 64;
            xb[nxt] = xp4[o];
            #pragma unroll
            for (int c = 0; c < CAND; ++c) wb[nxt][c] = wp[c][o];
        }
        const double dx = (double)xb[cur].x, dy = (double)xb[cur].y;
        const double dz = (double)xb[cur].z, dw = (double)xb[cur].w;
        #pragma unroll
        for (int c = 0; c < CAND; ++c) {
            const float4 wv = wb[cur][c];
            acc[2 * c]     = fma(dy, (double)wv.y, fma(dx, (double)wv.x, acc[2 * c]));
            acc[2 * c + 1] = fma(dw, (double)wv.w, fma(dz, (double)wv.z, acc[2 * c + 1]));
        }
    }

    double tot[CAND];
    #pragma unroll
    for (int c = 0; c < CAND; ++c) tot[c] = acc[2 * c] + acc[2 * c + 1];

    #pragma unroll
    for (int off = 32; off > 0; off >>= 1) {
        #pragma unroll
        for (int c = 0; c < CAND; ++c)
            tot[c] += __shfl_xor(tot[c], off, 64);
    }

    int rank[CAND];
    #pragma unroll
    for (int c = 0; c < CAND; ++c) {
        int r = 0;
        #pragma unroll
        for (int j = 0; j < CAND; ++j) {
            if (j == c) continue;
            if (tot[j] > tot[c] || (tot[j] == tot[c] && ce[j] < ce[c])) ++r;
        }
        rank[c] = r;
    }

    float sig[CAND];
    float sum = 0.f;
    #pragma unroll
    for (int c = 0; c < CAND; ++c) {
        sig[c] = 1.0f / (1.0f + expf(-(float)tot[c]));
        if (rank[c] < TOPK) sum += sig[c];
    }

    if (lane < TOPK) {
        float g = 0.f; int ei = 0;
        #pragma unroll
        for (int c = 0; c < CAND; ++c)
            if (rank[c] == lane) { g = sig[c]; ei = ce[c]; }
        out[(size_t)token * TOPK + lane] = g / sum;
        out[(size_t)TOKENS * TOPK + (size_t)token * TOPK + lane] = (float)ei;
    }
}

extern "C" void kernel_launch(void* const* d_in, const int* in_sizes, int n_in,
                              void* d_out, int out_size, void* d_ws, size_t ws_size,
                              hipStream_t stream) {
    const float* x = (const float*)d_in[0];   // [8192, 4096]
    const float* w = (const float*)d_in[1];   // [256, 4096]
    float* out     = (float*)d_out;

    const size_t plane = (size_t)TOKENS * NEXP * sizeof(float);   // 8 MB
    const size_t fixed = (size_t)TOKENS * CAND * sizeof(int)
                       + (size_t)NEXP * DIM * sizeof(_Float16);
    int S = 4;
    if (ws_size < 4 * plane + fixed) S = (ws_size >= 2 * plane + fixed) ? 2 : 1;

    float*     logits = (float*)d_ws;
    int*       candp  = (int*)((char*)d_ws + (size_t)S * plane);
    _Float16*  whs    = (_Float16*)((char*)candp + (size_t)TOKENS * CAND * sizeof(int));

    convert_w<<<512, 256, 0, stream>>>(w, whs);
    dim3 ggrid(TOKENS / MT4, S);
    gemm_v4<<<ggrid, 256, 0, stream>>>(x, whs, logits, DIM / S);
    topk_cand<<<TOKENS / 4, 256, 0, stream>>>(logits, candp, S);
    rescore<<<TOKENS / 4, 256, 0, stream>>>(x, w, candp, out);
}